// Round 2
// baseline (310.048 us; speedup 1.0000x reference)
//
#include <hip/hip_runtime.h>
#include <math.h>

#define TOKENS 16384
#define DMODEL 2048
#define NEXP   256
#define TOPK   8
#define BM     32
#define KC     256              // k-chunk (floats) staged in LDS per barrier pair
#define NCH    (DMODEL / KC)    // 8 chunks
#define RS     264              // LDS row stride in halfs (256 + 8 pad -> conflict-free)

typedef _Float16 f16;
typedef _Float16 f16x8 __attribute__((ext_vector_type(8)));
typedef _Float16 f16x4 __attribute__((ext_vector_type(4)));
typedef float    f32x4 __attribute__((ext_vector_type(4)));

// barrier that drains ONLY lgkm (LDS); global prefetch stays in flight
#define BAR() asm volatile("s_waitcnt lgkmcnt(0)\ns_barrier" ::: "memory")

// ---------------- prep: w (E x D f32) -> fp16 split planes, tile-major; also zero counts/ctr ----------------
// plane layout: idx = t*(NEXP*32) + e*32 + ki   (t = d>>5, ki = d&31)
__global__ void k_prep(const float* __restrict__ w,
                       f16* __restrict__ wsH, f16* __restrict__ wsL,
                       float* __restrict__ counts, unsigned* __restrict__ ctr) {
    if (blockIdx.x == 0) {
        counts[threadIdx.x] = 0.0f;
        if (threadIdx.x == 0 && ctr) *ctr = 0u;
    }
    int g  = blockIdx.x * 256 + threadIdx.x;
    int ki = g & 31;
    int e  = (g >> 5) & 255;
    int t  = g >> 13;
    float v = w[(size_t)e * DMODEL + t * 32 + ki] * 64.0f;
    f16 h = (f16)v;
    f16 l = (f16)((v - (float)h) * 2048.0f);
    wsH[g] = h;
    wsL[g] = l;
}

__global__ void k_zero(float* __restrict__ counts) {
    counts[threadIdx.x] = 0.0f;
}

// ---------------- main: chunked split-fp16 MFMA GEMM + top-8 + softmax + hist + (optional) stats ----------------
__global__ __launch_bounds__(256, 2) void k_main(
        const float* __restrict__ x,
        const f16*   __restrict__ wh,
        const f16*   __restrict__ wl,
        const float* __restrict__ bias,
        float* __restrict__ out,
        unsigned* __restrict__ ctr) {
    // A-chunk (hi+lo planes) and logits share the same LDS (union by lifetime)
    __shared__ __align__(16) char raw[2 * BM * RS * sizeof(f16)];   // 33792 B >= 32768 (logits)
    __shared__ float hist[NEXP];
    __shared__ unsigned lastflag;

    f16* AH = (f16*)raw;
    f16* AL = AH + BM * RS;
    float (*logits)[NEXP] = (float (*)[NEXP])raw;

    const int tid  = threadIdx.x;
    const int tok0 = blockIdx.x * BM;
    const int lane = tid & 63;
    const int wv   = tid >> 6;            // 0..3, owns experts wv*64..wv*64+63
    const int eb   = lane & 15;
    const int kq   = lane >> 4;           // 0..3

    hist[tid] = 0.0f;

    // ---- x staging map: thread -> (token tid>>3, k-lane (tid&7)*4 within each 32-wide seg) ----
    const int s_tok = tid >> 3;           // 0..31
    const int s_seg = tid & 7;            // 0..7
    const float* xb = x + (size_t)(tok0 + s_tok) * DMODEL + s_seg * 4;
    const int wbase = s_tok * RS + s_seg * 4;       // halfs

    // ---- A fragment read offsets (halfs): row m*16+eb, col kq*8 (+ j*32 per sub-tile) ----
    const int ro0 = eb * RS + kq * 8;
    const int ro1 = (16 + eb) * RS + kq * 8;

    // ---- B fragment offsets within a k-tile (halfs) ----
    size_t bo[4];
#pragma unroll
    for (int q = 0; q < 4; q++)
        bo[q] = (size_t)(((wv * 4 + q) * 16 + eb) * 32 + kq * 8);

    f32x4 acc0[2][4], acc1[2][4];
#pragma unroll
    for (int m = 0; m < 2; m++)
#pragma unroll
        for (int q = 0; q < 4; q++) {
            acc0[m][q] = (f32x4){0.0f, 0.0f, 0.0f, 0.0f};
            acc1[m][q] = (f32x4){0.0f, 0.0f, 0.0f, 0.0f};
        }

    // ---- prologue: load + stage chunk 0 ----
    float4 xr[8];
#pragma unroll
    for (int j = 0; j < 8; j++) xr[j] = *(const float4*)(xb + j * 32);
#pragma unroll
    for (int j = 0; j < 8; j++) {
        float4 v = xr[j];
        f16 h0 = (f16)v.x, h1 = (f16)v.y, h2 = (f16)v.z, h3 = (f16)v.w;
        f16x4 hv = {h0, h1, h2, h3};
        f16x4 lv = {(f16)((v.x - (float)h0) * 2048.0f),
                    (f16)((v.y - (float)h1) * 2048.0f),
                    (f16)((v.z - (float)h2) * 2048.0f),
                    (f16)((v.w - (float)h3) * 2048.0f)};
        *(f16x4*)(AH + wbase + j * 32) = hv;
        *(f16x4*)(AL + wbase + j * 32) = lv;
    }
    BAR();

    // ---- chunk loop: 2 lgkm-only barriers per chunk; x + B prefetch stay in flight ----
#pragma unroll 1
    for (int c = 0; c < NCH; ++c) {
        if (c < NCH - 1) {
#pragma unroll
            for (int j = 0; j < 8; j++)
                xr[j] = *(const float4*)(xb + (c + 1) * KC + j * 32);
        }
        const f16* whb = wh + (size_t)(c * 8) * (NEXP * 32);
        const f16* wlb = wl + (size_t)(c * 8) * (NEXP * 32);
        f16x8 bh[4], bl[4];
#pragma unroll
        for (int q = 0; q < 4; q++) {
            bh[q] = *(const f16x8*)(whb + bo[q]);
            bl[q] = *(const f16x8*)(wlb + bo[q]);
        }
#pragma unroll
        for (int j = 0; j < 8; ++j) {
            f16x8 nh[4], nl[4];
            if (j < 7) {
#pragma unroll
                for (int q = 0; q < 4; q++) {
                    nh[q] = *(const f16x8*)(whb + (size_t)(j + 1) * (NEXP * 32) + bo[q]);
                    nl[q] = *(const f16x8*)(wlb + (size_t)(j + 1) * (NEXP * 32) + bo[q]);
                }
            }
            const int co = j * 32;
            f16x8 a0h = *(const f16x8*)(AH + ro0 + co);
            f16x8 a1h = *(const f16x8*)(AH + ro1 + co);
            f16x8 a0l = *(const f16x8*)(AL + ro0 + co);
            f16x8 a1l = *(const f16x8*)(AL + ro1 + co);

            __builtin_amdgcn_s_setprio(1);
#pragma unroll
            for (int q = 0; q < 4; q++) {
                acc0[0][q] = __builtin_amdgcn_mfma_f32_16x16x32_f16(a0h, bh[q], acc0[0][q], 0, 0, 0);
                acc0[1][q] = __builtin_amdgcn_mfma_f32_16x16x32_f16(a1h, bh[q], acc0[1][q], 0, 0, 0);
            }
#pragma unroll
            for (int q = 0; q < 4; q++) {
                acc1[0][q] = __builtin_amdgcn_mfma_f32_16x16x32_f16(a0l, bh[q], acc1[0][q], 0, 0, 0);
                acc1[1][q] = __builtin_amdgcn_mfma_f32_16x16x32_f16(a1l, bh[q], acc1[1][q], 0, 0, 0);
            }
#pragma unroll
            for (int q = 0; q < 4; q++) {
                acc1[0][q] = __builtin_amdgcn_mfma_f32_16x16x32_f16(a0h, bl[q], acc1[0][q], 0, 0, 0);
                acc1[1][q] = __builtin_amdgcn_mfma_f32_16x16x32_f16(a1h, bl[q], acc1[1][q], 0, 0, 0);
            }
            __builtin_amdgcn_s_setprio(0);

            if (j < 7) {
#pragma unroll
                for (int q = 0; q < 4; q++) { bh[q] = nh[q]; bl[q] = nl[q]; }
            }
        }
        if (c < NCH - 1) {
            BAR();   // all waves done reading chunk c
#pragma unroll
            for (int j = 0; j < 8; j++) {
                float4 v = xr[j];
                f16 h0 = (f16)v.x, h1 = (f16)v.y, h2 = (f16)v.z, h3 = (f16)v.w;
                f16x4 hv = {h0, h1, h2, h3};
                f16x4 lv = {(f16)((v.x - (float)h0) * 2048.0f),
                            (f16)((v.y - (float)h1) * 2048.0f),
                            (f16)((v.z - (float)h2) * 2048.0f),
                            (f16)((v.w - (float)h3) * 2048.0f)};
                *(f16x4*)(AH + wbase + j * 32) = hv;
                *(f16x4*)(AL + wbase + j * 32) = lv;
            }
            BAR();   // chunk c+1 visible
        }
    }
    __syncthreads();   // protect LDS union before logits writes

    // ---- epilogue: descale + bias, write logits (C layout: col=lane&15, row=(lane>>4)*4+i) ----
#pragma unroll
    for (int m = 0; m < 2; m++) {
#pragma unroll
        for (int q = 0; q < 4; q++) {
            const int e = (wv * 4 + q) * 16 + eb;
            const float b = bias[e];
#pragma unroll
            for (int i = 0; i < 4; i++) {
                const int tk = m * 16 + kq * 4 + i;
                logits[tk][e] = (acc0[m][q][i] + acc1[m][q][i] * (1.0f / 2048.0f)) * (1.0f / 64.0f) + b;
            }
        }
    }
    __syncthreads();

    // ---- top-8 per token; each wave handles 8 tokens (verbatim from passing kernel) ----
    for (int tt = 0; tt < 8; tt++) {
        const int tok = wv * 8 + tt;
        float4 v4 = *(const float4*)&logits[tok][lane * 4];
        float lv[4] = {v4.x, v4.y, v4.z, v4.w};
        int msk = 0xF;
        float topv[TOPK];
        int   topi[TOPK];
#pragma unroll
        for (int r = 0; r < TOPK; r++) {
            float bvv = -INFINITY;
            int   bii = 0x7fffffff;
#pragma unroll
            for (int j = 0; j < 4; j++) {
                if (msk & (1 << j)) {
                    float vv = lv[j];
                    int   ii = lane * 4 + j;
                    if (vv > bvv || (vv == bvv && ii < bii)) { bvv = vv; bii = ii; }
                }
            }
#pragma unroll
            for (int off = 32; off > 0; off >>= 1) {
                float ov = __shfl_xor(bvv, off);
                int   oi = __shfl_xor(bii, off);
                if (ov > bvv || (ov == bvv && oi < bii)) { bvv = ov; bii = oi; }
            }
            topv[r] = bvv;
            topi[r] = bii;
            if ((bii >> 2) == lane) msk &= ~(1 << (bii & 3));
        }
        float m = topv[0];
        float s = 0.0f;
#pragma unroll
        for (int r = 0; r < TOPK; r++) s += expf(topv[r] - m);

        const int gtok = tok0 + tok;
        if (lane < TOPK) {
            out[(size_t)gtok * TOPK + lane] = expf(topv[lane] - m) / s;
        } else if (lane < 2 * TOPK) {
            int r = lane - TOPK;
            out[(size_t)TOKENS * TOPK + (size_t)gtok * TOPK + r] = (float)topi[r];
            atomicAdd(&hist[topi[r]], 1.0f);
        }
    }
    __syncthreads();
    float hv = hist[tid];
    if (hv != 0.0f) atomicAdd(&out[(size_t)2 * TOKENS * TOPK + tid], hv);

    // ---- fused stats: last block to finish computes them (saves a launch) ----
    if (ctr) {
        __threadfence();
        if (tid == 0) {
            unsigned d = atomicAdd(ctr, 1u);
            lastflag = (d == gridDim.x - 1) ? 1u : 0u;
        }
        __syncthreads();
        if (lastflag) {
            float* counts = out + (size_t)2 * TOKENS * TOPK;
            float c = atomicAdd(&counts[tid], 0.0f);   // coherent read of final count
            float* sm = hist;
            sm[tid] = c;
            __syncthreads();
            for (int s = 128; s > 0; s >>= 1) {
                if (tid < s) sm[tid] += sm[tid + s];
                __syncthreads();
            }
            float mean = sm[0] / (float)NEXP;
            __syncthreads();
            float d2 = c - mean;
            sm[tid] = d2 * d2;
            __syncthreads();
            for (int s = 128; s > 0; s >>= 1) {
                if (tid < s) sm[tid] += sm[tid + s];
                __syncthreads();
            }
            float var = sm[0] / (float)(NEXP - 1);
            __syncthreads();
            sm[tid] = c;
            __syncthreads();
            for (int s = 128; s > 0; s >>= 1) {
                if (tid < s) sm[tid] = fmaxf(sm[tid], sm[tid + s]);
                __syncthreads();
            }
            float mx = sm[0];
            __syncthreads();
            sm[tid] = c;
            __syncthreads();
            for (int s = 128; s > 0; s >>= 1) {
                if (tid < s) sm[tid] = fminf(sm[tid], sm[tid + s]);
                __syncthreads();
            }
            float mn = sm[0];
            if (tid == 0) {
                float* scal = counts + NEXP;
                scal[0] = sqrtf(var) / (mean + 1e-6f);
                scal[1] = mx;
                scal[2] = mn;
                scal[3] = (float)(TOKENS * TOPK) / (float)NEXP;
            }
        }
    }
}

// ---------------- fallback (no workspace): fp32 VALU kernel ----------------
__global__ __launch_bounds__(256, 3) void k_main_fb(
        const float* __restrict__ x,
        const float* __restrict__ wsrc,
        const float* __restrict__ bias,
        float* __restrict__ out) {
    __shared__ float xT[16][BM];
    __shared__ float wS[16][NEXP];
    __shared__ float logits[BM][NEXP];
    __shared__ float hist[NEXP];

    const int tid  = threadIdx.x;
    const int tok0 = blockIdx.x * BM;
    const int ty   = tid >> 5;
    const int tx   = tid & 31;

    hist[tid] = 0.0f;

    float acc[4][8];
#pragma unroll
    for (int i = 0; i < 4; i++)
#pragma unroll
        for (int j = 0; j < 8; j++) acc[i][j] = 0.0f;

    const int lx_tok = tid >> 3;
    const int lx_d   = (tid & 7) * 2;

    for (int k0 = 0; k0 < DMODEL; k0 += 16) {
        __syncthreads();
        float2 xv = *(const float2*)&x[(size_t)(tok0 + lx_tok) * DMODEL + k0 + lx_d];
        xT[lx_d][lx_tok]     = xv.x;
        xT[lx_d + 1][lx_tok] = xv.y;
#pragma unroll
        for (int i = 0; i < 16; i++)
            wS[i][tid] = wsrc[(size_t)tid * DMODEL + k0 + i];
        __syncthreads();
#pragma unroll
        for (int k = 0; k < 16; k++) {
            float4 a  = *(const float4*)&xT[k][ty * 4];
            float4 b0 = *(const float4*)&wS[k][tx * 8];
            float4 b1 = *(const float4*)&wS[k][tx * 8 + 4];
            float av[4] = {a.x, a.y, a.z, a.w};
            float bv[8] = {b0.x, b0.y, b0.z, b0.w, b1.x, b1.y, b1.z, b1.w};
#pragma unroll
            for (int i = 0; i < 4; i++)
#pragma unroll
                for (int j = 0; j < 8; j++)
                    acc[i][j] = fmaf(av[i], bv[j], acc[i][j]);
        }
    }

    float bb[8];
#pragma unroll
    for (int j = 0; j < 8; j++) bb[j] = bias[tx * 8 + j];
#pragma unroll
    for (int i = 0; i < 4; i++) {
#pragma unroll
        for (int j = 0; j < 8; j++)
            logits[ty * 4 + i][tx * 8 + j] = acc[i][j] + bb[j];
    }
    __syncthreads();

    const int lane = tid & 63;
    const int wv   = tid >> 6;
    for (int tt = 0; tt < 8; tt++) {
        const int tok = wv * 8 + tt;
        float4 v4 = *(const float4*)&logits[tok][lane * 4];
        float lv[4] = {v4.x, v4.y, v4.z, v4.w};
        int msk = 0xF;
        float topv[TOPK];
        int   topi[TOPK];
#pragma unroll
        for (int r = 0; r < TOPK; r++) {
            float bvv = -INFINITY;
            int   bii = 0x7fffffff;
#pragma unroll
            for (int j = 0; j < 4; j++) {
                if (msk & (1 << j)) {
                    float vv = lv[j];
                    int   ii = lane * 4 + j;
                    if (vv > bvv || (vv == bvv && ii < bii)) { bvv = vv; bii = ii; }
                }
            }
#pragma unroll
            for (int off = 32; off > 0; off >>= 1) {
                float ov = __shfl_xor(bvv, off);
                int   oi = __shfl_xor(bii, off);
                if (ov > bvv || (ov == bvv && oi < bii)) { bvv = ov; bii = oi; }
            }
            topv[r] = bvv;
            topi[r] = bii;
            if ((bii >> 2) == lane) msk &= ~(1 << (bii & 3));
        }
        float m = topv[0];
        float s = 0.0f;
#pragma unroll
        for (int r = 0; r < TOPK; r++) s += expf(topv[r] - m);

        const int gtok = tok0 + tok;
        if (lane < TOPK) {
            out[(size_t)gtok * TOPK + lane] = expf(topv[lane] - m) / s;
        } else if (lane < 2 * TOPK) {
            int r = lane - TOPK;
            out[(size_t)TOKENS * TOPK + (size_t)gtok * TOPK + r] = (float)topi[r];
            atomicAdd(&hist[topi[r]], 1.0f);
        }
    }
    __syncthreads();
    float hv = hist[tid];
    if (hv != 0.0f) atomicAdd(&out[(size_t)2 * TOKENS * TOPK + tid], hv);
}

// ---------------- stats kernel (used when ws has no room for the done-counter) ----------------
__global__ void k_stats(float* __restrict__ out) {
    __shared__ float sm[NEXP];
    const float* counts = out + (size_t)2 * TOKENS * TOPK;
    const int t = threadIdx.x;
    float c = counts[t];

    sm[t] = c;
    __syncthreads();
    for (int s = 128; s > 0; s >>= 1) {
        if (t < s) sm[t] += sm[t + s];
        __syncthreads();
    }
    float mean = sm[0] / (float)NEXP;
    __syncthreads();

    float d = c - mean;
    sm[t] = d * d;
    __syncthreads();
    for (int s = 128; s > 0; s >>= 1) {
        if (t < s) sm[t] += sm[t + s];
        __syncthreads();
    }
    float var = sm[0] / (float)(NEXP - 1);
    __syncthreads();

    sm[t] = c;
    __syncthreads();
    for (int s = 128; s > 0; s >>= 1) {
        if (t < s) sm[t] = fmaxf(sm[t], sm[t + s]);
        __syncthreads();
    }
    float mx = sm[0];
    __syncthreads();

    sm[t] = c;
    __syncthreads();
    for (int s = 128; s > 0; s >>= 1) {
        if (t < s) sm[t] = fminf(sm[t], sm[t + s]);
        __syncthreads();
    }
    float mn = sm[0];

    if (t == 0) {
        float* scal = out + (size_t)2 * TOKENS * TOPK + NEXP;
        scal[0] = sqrtf(var) / (mean + 1e-6f);
        scal[1] = mx;
        scal[2] = mn;
        scal[3] = (float)(TOKENS * TOPK) / (float)NEXP;
    }
}

extern "C" void kernel_launch(void* const* d_in, const int* in_sizes, int n_in,
                              void* d_out, int out_size, void* d_ws, size_t ws_size,
                              hipStream_t stream) {
    const float* x    = (const float*)d_in[0];
    const float* w    = (const float*)d_in[1];
    const float* bias = (const float*)d_in[2];
    float* out = (float*)d_out;
    float* counts = out + (size_t)2 * TOKENS * TOPK;

    const size_t need = (size_t)DMODEL * NEXP * 2 * sizeof(_Float16);  // 2 MB
    if (ws_size >= need) {
        f16* wsH = (f16*)d_ws;
        f16* wsL = wsH + (size_t)DMODEL * NEXP;
        unsigned* ctr = (ws_size >= need + 64)
                            ? (unsigned*)((char*)d_ws + need) : (unsigned*)0;
        k_prep<<<(DMODEL * NEXP) / 256, 256, 0, stream>>>(w, wsH, wsL, counts, ctr);
        k_main<<<TOKENS / BM, 256, 0, stream>>>(x, wsH, wsL, bias, out, ctr);
        if (!ctr) k_stats<<<1, NEXP, 0, stream>>>(out);
    } else {
        k_zero<<<1, NEXP, 0, stream>>>(counts);
        k_main_fb<<<TOKENS / BM, 256, 0, stream>>>(x, w, bias, out);
        k_stats<<<1, NEXP, 0, stream>>>(out);
    }
}